// Round 1
// baseline (334.454 us; speedup 1.0000x reference)
//
#include <hip/hip_runtime.h>

typedef unsigned short ushort_t;
typedef float f32x4 __attribute__((ext_vector_type(4)));
typedef short short8 __attribute__((ext_vector_type(8)));

#define NB 32
#define NP 576
#define ND 768
#define NH 12
#define NHD 64

// workspace layout (bytes); total = 60,162,048
#define WT_BYTES (3*12*64*768*2)          // 3,538,944   Wt[proj][h][hd][d] bf16
#define K_BYTES  (32*12*576*64*2)         // 28,311,552  K[b][h][p][hd] bf16
// V^T[b][h][hd][p] bf16 follows K

static __device__ __forceinline__ ushort_t f2bf(float f) {
    return __builtin_bit_cast(ushort_t, (__bf16)f);
}

// ---------------------------------------------------------------------------
// Kernel 1: convert + transpose weights: Wt[proj][h][hd][d] (bf16)
// ---------------------------------------------------------------------------
__global__ __launch_bounds__(256) void prep_weights(
    const float* __restrict__ Wq, const float* __restrict__ Wk,
    const float* __restrict__ Wv, ushort_t* __restrict__ Wt)
{
    int idx = blockIdx.x * 256 + threadIdx.x;        // 3*12*768*64 = 1,769,472
    int hd   = idx & 63;
    int rest = idx >> 6;          // ph*768 + d
    int d    = rest % 768;
    int ph   = rest / 768;        // proj*12 + h
    int h    = ph % 12;
    int pr   = ph / 12;
    const float* W = (pr == 0) ? Wq : (pr == 1 ? Wk : Wv);
    float v = W[(h * 768 + d) * 64 + hd];
    Wt[((size_t)ph * 64 + hd) * 768 + d] = f2bf(v);
}

// ---------------------------------------------------------------------------
// Kernel 2: K = x@Wk + bk  ->  K[b][h][p][hd] bf16
//           V = x@Wv + bv  ->  Vt[b][h][hd][p] bf16 (transposed via LDS)
// block: 256 thr (4 waves); computes one 64(token)x64(hd) tile, K-loop D=768
// ---------------------------------------------------------------------------
__global__ __launch_bounds__(256) void proj_kv(
    const float* __restrict__ x, const ushort_t* __restrict__ Wt,
    const float* __restrict__ bk, const float* __restrict__ bv,
    ushort_t* __restrict__ Kb, ushort_t* __restrict__ Vtb)
{
    __shared__ ushort_t sA[64][72];   // x tile [token][d]  (pad 72: 144B rows, 16B aligned)
    __shared__ ushort_t sB[64][72];   // W tile [hd][d]

    const int t   = threadIdx.x;
    const int hp  = blockIdx.x;            // h*2 + proj  (24)
    const int h   = hp >> 1, proj = hp & 1;
    const int bt  = blockIdx.y;            // b*9 + ptile (288)
    const int b   = bt / 9,  pt = bt % 9;
    const int p0  = pt * 64;
    const int w   = t >> 6, l = t & 63, m16 = l & 15, g = l >> 4;
    const int sr  = t >> 2, scc = (t & 3) * 16;

    const float*    xrow = x  + ((size_t)b * NP + p0 + sr) * ND;
    const ushort_t* wrow = Wt + (((size_t)(1 + proj) * 12 + h) * 64 + sr) * ND;

    f32x4 acc[4] = {};

    for (int kc = 0; kc < 12; ++kc) {
        // stage x tile (fp32 -> bf16): thread loads 16 floats of its row chunk
        const float4* xp = (const float4*)(xrow + kc * 64 + scc);
        float4 v0 = xp[0], v1 = xp[1], v2 = xp[2], v3 = xp[3];
        union { ushort_t u[8]; short8 v; } pk;
        pk.u[0]=f2bf(v0.x); pk.u[1]=f2bf(v0.y); pk.u[2]=f2bf(v0.z); pk.u[3]=f2bf(v0.w);
        pk.u[4]=f2bf(v1.x); pk.u[5]=f2bf(v1.y); pk.u[6]=f2bf(v1.z); pk.u[7]=f2bf(v1.w);
        *(short8*)&sA[sr][scc] = pk.v;
        pk.u[0]=f2bf(v2.x); pk.u[1]=f2bf(v2.y); pk.u[2]=f2bf(v2.z); pk.u[3]=f2bf(v2.w);
        pk.u[4]=f2bf(v3.x); pk.u[5]=f2bf(v3.y); pk.u[6]=f2bf(v3.z); pk.u[7]=f2bf(v3.w);
        *(short8*)&sA[sr][scc + 8] = pk.v;
        // stage W tile (already bf16)
        const short8* wp = (const short8*)(wrow + kc * 64 + scc);
        *(short8*)&sB[sr][scc]     = wp[0];
        *(short8*)&sB[sr][scc + 8] = wp[1];
        __syncthreads();
        #pragma unroll
        for (int j = 0; j < 2; ++j) {
            short8 a = *(const short8*)&sA[w * 16 + m16][j * 32 + g * 8];
            #pragma unroll
            for (int f = 0; f < 4; ++f) {
                short8 bb = *(const short8*)&sB[f * 16 + m16][j * 32 + g * 8];
                acc[f] = __builtin_amdgcn_mfma_f32_16x16x32_bf16(a, bb, acc[f], 0, 0, 0);
            }
        }
        __syncthreads();
    }

    // epilogue: bias, bf16, into LDS as [token][hd] (K) or [hd][token] (V)
    const float* bias = (proj == 0 ? bk : bv) + h * 64;
    #pragma unroll
    for (int f = 0; f < 4; ++f) {
        float bvv = bias[f * 16 + m16];
        #pragma unroll
        for (int i = 0; i < 4; ++i) {
            float val = acc[f][i] + bvv;
            int row = w * 16 + g * 4 + i;   // token (local)
            int col = f * 16 + m16;         // hd
            if (proj == 0) sA[row][col] = f2bf(val);
            else           sA[col][row] = f2bf(val);
        }
    }
    __syncthreads();
    // coalesced store: row o = sr, 16 elems from scc
    ushort_t* dst; size_t ld;
    if (proj == 0) { dst = Kb  + ((size_t)(b * NH + h) * NP + p0) * NHD; ld = NHD; }
    else           { dst = Vtb + ((size_t)(b * NH + h) * NHD) * NP + p0; ld = NP;  }
    *(short8*)(dst + (size_t)sr * ld + scc)     = *(const short8*)&sA[sr][scc];
    *(short8*)(dst + (size_t)sr * ld + scc + 8) = *(const short8*)&sA[sr][scc + 8];
}

// ---------------------------------------------------------------------------
// Kernel 3: fused Q-projection + flash attention per (qtile, b*h)
// ---------------------------------------------------------------------------
__global__ __launch_bounds__(256) void attn(
    const float* __restrict__ x, const ushort_t* __restrict__ Wt,
    const float* __restrict__ bq, const ushort_t* __restrict__ Kb,
    const ushort_t* __restrict__ Vtb, float* __restrict__ out)
{
    __shared__ ushort_t sA[64][72];        // x tile -> Q staging -> K tiles
    __shared__ ushort_t sB[64][72];        // Wq tile -> V^T tiles
    __shared__ ushort_t sP[4][16][72];     // per-wave P re-fragment buffer

    const int t   = threadIdx.x;
    const int qt  = blockIdx.x;            // 9
    const int bh  = blockIdx.y;            // 384
    const int b   = bh / NH, h = bh % NH;
    const int p0  = qt * 64;
    const int w   = t >> 6, l = t & 63, m16 = l & 15, g = l >> 4;
    const int sr  = t >> 2, scc = (t & 3) * 16;

    // ---- Q projection (identical GEMM loop) ----
    const float*    xrow = x  + ((size_t)b * NP + p0 + sr) * ND;
    const ushort_t* wrow = Wt + ((size_t)h * 64 + sr) * ND;   // proj 0 = Q
    f32x4 acc[4] = {};
    for (int kc = 0; kc < 12; ++kc) {
        const float4* xp = (const float4*)(xrow + kc * 64 + scc);
        float4 v0 = xp[0], v1 = xp[1], v2 = xp[2], v3 = xp[3];
        union { ushort_t u[8]; short8 v; } pk;
        pk.u[0]=f2bf(v0.x); pk.u[1]=f2bf(v0.y); pk.u[2]=f2bf(v0.z); pk.u[3]=f2bf(v0.w);
        pk.u[4]=f2bf(v1.x); pk.u[5]=f2bf(v1.y); pk.u[6]=f2bf(v1.z); pk.u[7]=f2bf(v1.w);
        *(short8*)&sA[sr][scc] = pk.v;
        pk.u[0]=f2bf(v2.x); pk.u[1]=f2bf(v2.y); pk.u[2]=f2bf(v2.z); pk.u[3]=f2bf(v2.w);
        pk.u[4]=f2bf(v3.x); pk.u[5]=f2bf(v3.y); pk.u[6]=f2bf(v3.z); pk.u[7]=f2bf(v3.w);
        *(short8*)&sA[sr][scc + 8] = pk.v;
        const short8* wp = (const short8*)(wrow + kc * 64 + scc);
        *(short8*)&sB[sr][scc]     = wp[0];
        *(short8*)&sB[sr][scc + 8] = wp[1];
        __syncthreads();
        #pragma unroll
        for (int j = 0; j < 2; ++j) {
            short8 a = *(const short8*)&sA[w * 16 + m16][j * 32 + g * 8];
            #pragma unroll
            for (int f = 0; f < 4; ++f) {
                short8 bb = *(const short8*)&sB[f * 16 + m16][j * 32 + g * 8];
                acc[f] = __builtin_amdgcn_mfma_f32_16x16x32_bf16(a, bb, acc[f], 0, 0, 0);
            }
        }
        __syncthreads();
    }
    // Q -> LDS [token][hd], scaled by 1/sqrt(64) and biased
    #pragma unroll
    for (int f = 0; f < 4; ++f) {
        float bqv = bq[h * 64 + f * 16 + m16];
        #pragma unroll
        for (int i = 0; i < 4; ++i)
            sA[w * 16 + g * 4 + i][f * 16 + m16] = f2bf((acc[f][i] + bqv) * 0.125f);
    }
    __syncthreads();
    // Q A-fragments for QK^T (wave w owns q-rows w*16..w*16+15), kept in regs
    short8 aq0 = *(const short8*)&sA[w * 16 + m16][g * 8];
    short8 aq1 = *(const short8*)&sA[w * 16 + m16][32 + g * 8];

    float mrun[4], lrun[4];
    f32x4 accO[4] = {};
    #pragma unroll
    for (int i = 0; i < 4; ++i) { mrun[i] = -1e30f; lrun[i] = 0.f; }

    const ushort_t* Kbase = Kb  + (size_t)bh * NP * NHD;
    const ushort_t* Vbase = Vtb + ((size_t)bh * NHD + sr) * NP;

    for (int kt = 0; kt < 9; ++kt) {
        __syncthreads();   // previous iter's LDS reads complete
        // stage K tile [key][hd] and V^T tile [hd][key]
        const short8* kp = (const short8*)(Kbase + (size_t)(kt * 64 + sr) * NHD + scc);
        *(short8*)&sA[sr][scc]     = kp[0];
        *(short8*)&sA[sr][scc + 8] = kp[1];
        const short8* vp = (const short8*)(Vbase + kt * 64 + scc);
        *(short8*)&sB[sr][scc]     = vp[0];
        *(short8*)&sB[sr][scc + 8] = vp[1];
        __syncthreads();

        // S = Q K^T  (16 q-rows x 64 keys per wave)
        f32x4 s[4] = {};
        #pragma unroll
        for (int j = 0; j < 2; ++j) {
            short8 aqj = j ? aq1 : aq0;
            #pragma unroll
            for (int f = 0; f < 4; ++f) {
                short8 bk_ = *(const short8*)&sA[f * 16 + m16][j * 32 + g * 8];
                s[f] = __builtin_amdgcn_mfma_f32_16x16x32_bf16(aqj, bk_, s[f], 0, 0, 0);
            }
        }

        // online softmax: rows r = g*4+i live in the 16 lanes of group g
        float tmax[4], scal[4], tsum[4];
        #pragma unroll
        for (int i = 0; i < 4; ++i)
            tmax[i] = fmaxf(fmaxf(s[0][i], s[1][i]), fmaxf(s[2][i], s[3][i]));
        #pragma unroll
        for (int xm = 1; xm < 16; xm <<= 1) {
            #pragma unroll
            for (int i = 0; i < 4; ++i)
                tmax[i] = fmaxf(tmax[i], __shfl_xor(tmax[i], xm, 64));
        }
        #pragma unroll
        for (int i = 0; i < 4; ++i) {
            float mnew = fmaxf(mrun[i], tmax[i]);
            scal[i] = __expf(mrun[i] - mnew);
            mrun[i] = mnew;
        }
        #pragma unroll
        for (int f = 0; f < 4; ++f)
            #pragma unroll
            for (int i = 0; i < 4; ++i)
                s[f][i] = __expf(s[f][i] - mrun[i]);
        #pragma unroll
        for (int i = 0; i < 4; ++i)
            tsum[i] = s[0][i] + s[1][i] + s[2][i] + s[3][i];
        #pragma unroll
        for (int xm = 1; xm < 16; xm <<= 1) {
            #pragma unroll
            for (int i = 0; i < 4; ++i)
                tsum[i] += __shfl_xor(tsum[i], xm, 64);
        }
        #pragma unroll
        for (int i = 0; i < 4; ++i)
            lrun[i] = lrun[i] * scal[i] + tsum[i];
        #pragma unroll
        for (int f = 0; f < 4; ++f)
            #pragma unroll
            for (int i = 0; i < 4; ++i)
                accO[f][i] *= scal[i];

        // P -> per-wave LDS, re-read as A-fragments
        #pragma unroll
        for (int f = 0; f < 4; ++f)
            #pragma unroll
            for (int i = 0; i < 4; ++i)
                sP[w][g * 4 + i][f * 16 + m16] = f2bf(s[f][i]);
        __syncthreads();
        short8 pa0 = *(const short8*)&sP[w][m16][g * 8];
        short8 pa1 = *(const short8*)&sP[w][m16][32 + g * 8];

        // O += P V
        #pragma unroll
        for (int j = 0; j < 2; ++j) {
            short8 paj = j ? pa1 : pa0;
            #pragma unroll
            for (int f = 0; f < 4; ++f) {
                short8 bv_ = *(const short8*)&sB[f * 16 + m16][j * 32 + g * 8];
                accO[f] = __builtin_amdgcn_mfma_f32_16x16x32_bf16(paj, bv_, accO[f], 0, 0, 0);
            }
        }
    }

    // epilogue: normalize and store (out[b][p][h*64+hd], fp32)
    float inv[4];
    #pragma unroll
    for (int i = 0; i < 4; ++i) inv[i] = 1.0f / lrun[i];
    float* orow = out + ((size_t)b * NP + p0 + w * 16) * ND + h * NHD;
    #pragma unroll
    for (int f = 0; f < 4; ++f)
        #pragma unroll
        for (int i = 0; i < 4; ++i)
            orow[(size_t)(g * 4 + i) * ND + f * 16 + m16] = accO[f][i] * inv[i];
}

extern "C" void kernel_launch(void* const* d_in, const int* in_sizes, int n_in,
                              void* d_out, int out_size, void* d_ws, size_t ws_size,
                              hipStream_t stream) {
    const float* x  = (const float*)d_in[0];
    const float* Wq = (const float*)d_in[1];
    const float* bq = (const float*)d_in[2];
    const float* Wk = (const float*)d_in[3];
    const float* bk = (const float*)d_in[4];
    const float* Wv = (const float*)d_in[5];
    const float* bv = (const float*)d_in[6];
    float* out = (float*)d_out;

    ushort_t* Wt  = (ushort_t*)d_ws;                                    // 3.54 MB
    ushort_t* Kb  = (ushort_t*)((char*)d_ws + WT_BYTES);                // 28.3 MB
    ushort_t* Vtb = (ushort_t*)((char*)d_ws + WT_BYTES + K_BYTES);     // 28.3 MB
    // requires ws_size >= 60,162,048 bytes

    hipLaunchKernelGGL(prep_weights, dim3(6912), dim3(256), 0, stream, Wq, Wk, Wv, Wt);
    hipLaunchKernelGGL(proj_kv, dim3(24, 288), dim3(256), 0, stream,
                       x, Wt, bk, bv, Kb, Vtb);
    hipLaunchKernelGGL(attn, dim3(9, 384), dim3(256), 0, stream,
                       x, Wt, bq, Kb, Vtb, out);
}

// Round 2
// 231.545 us; speedup vs baseline: 1.4444x; 1.4444x over previous
//
#include <hip/hip_runtime.h>

typedef unsigned short ushort_t;
typedef unsigned int u32;
typedef float f32x4 __attribute__((ext_vector_type(4)));
typedef short short8 __attribute__((ext_vector_type(8)));

#define NB 32
#define NP 576
#define ND 768
#define NH 12
#define NHD 64

#define WT_BYTES  (36*64*768*2)            // 3,538,944
#define KV_BYTES  (32*12*576*64*2)         // 28,311,552 each for Q,K,Vt
#define QSCALE    0.18033688f              // 0.125 * log2(e)

static __device__ __forceinline__ ushort_t f2bf(float f) {
    return __builtin_bit_cast(ushort_t, (__bf16)f);
}
static __device__ __forceinline__ short8 pack8(float4 a, float4 b) {
    union { ushort_t u[8]; short8 v; } pk;
    pk.u[0]=f2bf(a.x); pk.u[1]=f2bf(a.y); pk.u[2]=f2bf(a.z); pk.u[3]=f2bf(a.w);
    pk.u[4]=f2bf(b.x); pk.u[5]=f2bf(b.y); pk.u[6]=f2bf(b.z); pk.u[7]=f2bf(b.w);
    return pk.v;
}
// async global->LDS, 16B per lane; LDS dest must be wave-uniform (lane i -> dest + 16*i)
static __device__ __forceinline__ void gl_lds16(const ushort_t* g, ushort_t* l) {
    __builtin_amdgcn_global_load_lds((const __attribute__((address_space(1))) u32*)g,
                                     (__attribute__((address_space(3))) u32*)l, 16, 0, 0);
}
// byte offset of (row, 16B-chunk) in a [rows][64]bf16 tile with XOR swizzle
static __device__ __forceinline__ int swzb(int row, int chunk) {
    return row * 128 + (((chunk ^ (row & 7)) & 7) << 4);
}
#define MFMA16 __builtin_amdgcn_mfma_f32_16x16x32_bf16

// ---------------------------------------------------------------------------
// Kernel 1: weights -> Wt[ph=proj*12+h][hd][d] bf16  (ph 0..35: Q,K,V)
// ---------------------------------------------------------------------------
__global__ __launch_bounds__(256) void prep_w(
    const float* __restrict__ Wq, const float* __restrict__ Wk,
    const float* __restrict__ Wv, ushort_t* __restrict__ Wt)
{
    int idx = blockIdx.x * 256 + threadIdx.x;    // 221,184 chunks of 8 d
    int d0   = (idx % 96) * 8;
    int rest = idx / 96;
    int hd   = rest & 63;
    int ph   = rest >> 6;                        // 0..35
    int h    = ph % 12, pr = ph / 12;
    const float* W = (pr == 0) ? Wq : (pr == 1 ? Wk : Wv);
    union { ushort_t u[8]; short8 v; } pk;
    #pragma unroll
    for (int j = 0; j < 8; ++j)
        pk.u[j] = f2bf(W[(size_t)(h * 768 + d0 + j) * 64 + hd]);
    *(short8*)(Wt + ((size_t)(ph * 64 + hd)) * 768 + d0) = pk.v;
}

// ---------------------------------------------------------------------------
// Kernel 2: QKV projection GEMM. M-tile 96 tokens x N-tile 128 (2 proj-heads).
// A: x fp32 -> bf16 reg-staged (swizzled ds_write); B: Wt via global_load_lds
// (pre-swizzled source). Q/K -> [bh][p][hd]; V -> [bh][hd][p] (LDS transpose).
// Q gets (x+bias)*QSCALE baked in.
// ---------------------------------------------------------------------------
__global__ __launch_bounds__(256) void proj_qkv(
    const float* __restrict__ x, const ushort_t* __restrict__ Wt,
    const float* __restrict__ bq, const float* __restrict__ bk,
    const float* __restrict__ bv,
    ushort_t* __restrict__ Qb, ushort_t* __restrict__ Kb,
    ushort_t* __restrict__ Vtb, int nts, int ph_base)
{
    __shared__ ushort_t smem[18432];   // 36,864 B: A[96][64]@0 (12,288B), B[128][64]@12,288; epilogue [4][64][72]

    const int t = threadIdx.x;
    const int w = t >> 6, l = t & 63, m16 = l & 15, g = l >> 4;
    const int wm = w >> 1, wn = w & 1;

    // XCD swizzle: blocks sharing an A (x) panel land on one XCD
    int L = blockIdx.y * gridDim.x + blockIdx.x;
    int xcd = L & 7, jj_ = L >> 3;
    int nt = jj_ % nts, mt = (jj_ / nts) * 8 + xcd;
    const int m0 = mt * 96;
    const int b  = mt / 6, pb = (mt % 6) * 96;

    const int grow = l >> 3, gch = (l & 7) ^ grow;   // pre-swizzled source chunk

    f32x4 acc[3][4] = {};

    for (int kc = 0; kc < 12; ++kc) {
        const int k0 = kc * 64;
        __syncthreads();
        // A stage: 96x64 fp32 -> bf16, swizzled ds_write_b128
        #pragma unroll
        for (int q = 0; q < 3; ++q) {
            int c = t + q * 256;
            int row = c >> 3, ch = c & 7;
            const float4* xp = (const float4*)(x + (size_t)(m0 + row) * 768 + k0 + ch * 8);
            *(short8*)((char*)smem + swzb(row, ch)) = pack8(xp[0], xp[1]);
        }
        // B stage: 16KB via global_load_lds (4 chunks of 1KB per wave)
        #pragma unroll
        for (int c4 = 0; c4 < 4; ++c4) {
            int ci = w * 4 + c4;
            const ushort_t* gs = Wt + (size_t)(ph_base * 64 + nt * 128 + ci * 8 + grow) * 768
                               + k0 + gch * 8;
            gl_lds16(gs, smem + 6144 + ci * 512);
        }
        __syncthreads();
        // 24 MFMA / wave
        #pragma unroll
        for (int jj = 0; jj < 2; ++jj) {
            short8 af[3], bf[4];
            #pragma unroll
            for (int mi = 0; mi < 3; ++mi)
                af[mi] = *(const short8*)((char*)smem + swzb(wm * 48 + mi * 16 + m16, jj * 4 + g));
            #pragma unroll
            for (int ni = 0; ni < 4; ++ni)
                bf[ni] = *(const short8*)((char*)smem + 12288 + swzb(wn * 64 + ni * 16 + m16, jj * 4 + g));
            #pragma unroll
            for (int mi = 0; mi < 3; ++mi)
                #pragma unroll
                for (int ni = 0; ni < 4; ++ni)
                    acc[mi][ni] = MFMA16(af[mi], bf[ni], acc[mi][ni], 0, 0, 0);
        }
    }
    __syncthreads();   // all frag reads done; safe to reuse smem as epilogue buffer

    const int ph = ph_base + nt * 2 + wn;
    const int proj = ph / 12, h = ph % 12;
    const float* bias = (proj == 0 ? bq : (proj == 1 ? bk : bv)) + h * 64;
    const float qs = (proj == 0) ? QSCALE : 1.0f;
    ushort_t* sE = smem + w * 4608;    // per-wave 64x72 bf16 (wave-private)

    #pragma unroll
    for (int ni = 0; ni < 4; ++ni) {
        float bvv = bias[ni * 16 + m16];
        #pragma unroll
        for (int mi = 0; mi < 3; ++mi)
            #pragma unroll
            for (int i = 0; i < 4; ++i) {
                float val = (acc[mi][ni][i] + bvv) * qs;
                int tok = mi * 16 + g * 4 + i;    // 0..47
                int hd  = ni * 16 + m16;          // 0..63
                if (proj < 2) sE[tok * 72 + hd] = f2bf(val);
                else          sE[hd * 72 + tok] = f2bf(val);
            }
    }
    if (proj < 2) {
        ushort_t* dst = (proj == 0 ? Qb : Kb)
                      + ((size_t)(b * 12 + h) * 576 + pb + wm * 48) * 64;
        #pragma unroll
        for (int rr = 0; rr < 6; ++rr) {
            int row = rr * 8 + (l >> 3), ch = l & 7;
            *(short8*)(dst + (size_t)row * 64 + ch * 8) = *(const short8*)&sE[row * 72 + ch * 8];
        }
    } else {
        ushort_t* dst = Vtb + (size_t)(b * 12 + h) * 64 * 576 + pb + wm * 48;
        #pragma unroll
        for (int rr = 0; rr < 8; ++rr) {
            int hd = rr * 8 + (l >> 3), tc = l & 7;
            if (tc < 6)
                *(short8*)(dst + (size_t)hd * 576 + tc * 8) = *(const short8*)&sE[hd * 72 + tc * 8];
        }
    }
}

// ---------------------------------------------------------------------------
// Kernel 3: flash attention. FUSEQ=1 computes Q in-kernel (small-ws fallback);
// FUSEQ=0 loads precomputed Q fragments. K/V double-buffered via
// global_load_lds, 1 barrier/iter; P buffer wave-private (no barrier).
// ---------------------------------------------------------------------------
template<int FUSEQ>
__global__ __launch_bounds__(256) void attn_k(
    const float* __restrict__ x, const ushort_t* __restrict__ Wt,
    const float* __restrict__ bq, const ushort_t* __restrict__ Qb,
    const ushort_t* __restrict__ Kb, const ushort_t* __restrict__ Vtb,
    float* __restrict__ out)
{
    // 40,960 B: K tiles [2][64][64]@0, V tiles [2][64][64]@16384, sP [4][16][64]@32768
    __shared__ ushort_t smem[20480];

    const int t = threadIdx.x;
    const int w = t >> 6, l = t & 63, m16 = l & 15, g = l >> 4;

    // XCD swizzle: 9 qtile-blocks of one (b,h) land on one XCD -> K/V L2 reuse
    int L = blockIdx.y * 9 + blockIdx.x;
    int xcd = L & 7, jj_ = L >> 3;
    int qt = jj_ % 9, bh = (jj_ / 9) * 8 + xcd;
    const int b = bh / 12, h = bh % 12;
    const int p0 = qt * 64;

    const int grow = l >> 3, gch = (l & 7) ^ grow;
    const int spbase = 32768 + w * 2048;     // wave-private P region (bytes)

    short8 aq0, aq1;

    if constexpr (FUSEQ) {
        f32x4 acc[4] = {};
        const int row = t >> 2, c16 = (t & 3) * 16;
        // stage x chunk (reg convert, swizzled) + Wq chunk (gload_lds) into buf d
        auto stage = [&](int kc, int d) {
            const float4* xp = (const float4*)(x + (size_t)(b * 576 + p0 + row) * 768 + kc * 64 + c16);
            float4 u0 = xp[0], u1 = xp[1], u2 = xp[2], u3 = xp[3];
            *(short8*)((char*)smem + d * 8192 + swzb(row, c16 >> 3))       = pack8(u0, u1);
            *(short8*)((char*)smem + d * 8192 + swzb(row, (c16 >> 3) + 1)) = pack8(u2, u3);
            #pragma unroll
            for (int c2 = 0; c2 < 2; ++c2) {
                int ci = w * 2 + c2;
                const ushort_t* gs = Wt + (size_t)(h * 64 + ci * 8 + grow) * 768 + kc * 64 + gch * 8;
                gl_lds16(gs, smem + (16384 + d * 8192 + ci * 1024) / 2);
            }
        };
        stage(0, 0); __syncthreads();
        for (int kc = 0; kc < 12; ++kc) {
            int d = kc & 1;
            if (kc < 11) stage(kc + 1, d ^ 1);
            #pragma unroll
            for (int jj = 0; jj < 2; ++jj) {
                short8 a = *(const short8*)((char*)smem + d * 8192 + swzb(w * 16 + m16, jj * 4 + g));
                #pragma unroll
                for (int f = 0; f < 4; ++f) {
                    short8 bb = *(const short8*)((char*)smem + 16384 + d * 8192 + swzb(f * 16 + m16, jj * 4 + g));
                    acc[f] = MFMA16(a, bb, acc[f], 0, 0, 0);
                }
            }
            __syncthreads();
        }
        // Q -> wave-private sP (scaled+biased), re-read as A fragments
        #pragma unroll
        for (int f = 0; f < 4; ++f) {
            float bqv = bq[h * 64 + f * 16 + m16];
            #pragma unroll
            for (int i = 0; i < 4; ++i) {
                float val = (acc[f][i] + bqv) * QSCALE;
                int r = g * 4 + i, c = f * 16 + m16;
                *(ushort_t*)((char*)smem + spbase + r * 128
                    + (((((c >> 3) ^ (r & 7)) & 7) << 4) | ((c & 7) << 1))) = f2bf(val);
            }
        }
        aq0 = *(const short8*)((char*)smem + spbase + m16 * 128 + (((g ^ (m16 & 7)) & 7) << 4));
        aq1 = *(const short8*)((char*)smem + spbase + m16 * 128 + ((((4 + g) ^ (m16 & 7)) & 7) << 4));
    } else {
        const ushort_t* qsrc = Qb + ((size_t)bh * 576 + p0 + w * 16 + m16) * 64 + g * 8;
        aq0 = *(const short8*)qsrc;
        aq1 = *(const short8*)(qsrc + 32);
    }

    const ushort_t* Kbase = Kb  + (size_t)bh * (576 * 64);
    const ushort_t* Vbase = Vtb + (size_t)bh * (64 * 576);

    auto stageKV = [&](int kt, int d) {
        #pragma unroll
        for (int c2 = 0; c2 < 2; ++c2) {
            int ci = w * 2 + c2;
            gl_lds16(Kbase + (size_t)(kt * 64 + ci * 8 + grow) * 64 + gch * 8,
                     smem + (d * 8192 + ci * 1024) / 2);
            gl_lds16(Vbase + (size_t)(ci * 8 + grow) * 576 + kt * 64 + gch * 8,
                     smem + (16384 + d * 8192 + ci * 1024) / 2);
        }
    };

    float mrun[4], lrun[4];
    f32x4 accO[4] = {};
    #pragma unroll
    for (int i = 0; i < 4; ++i) { mrun[i] = -1e30f; lrun[i] = 0.f; }

    stageKV(0, 0); __syncthreads();
    for (int kt = 0; kt < 9; ++kt) {
        int d = kt & 1;
        if (kt < 8) stageKV(kt + 1, d ^ 1);

        // S = Q K^T
        f32x4 s[4] = {};
        #pragma unroll
        for (int jj = 0; jj < 2; ++jj) {
            short8 aqj = jj ? aq1 : aq0;
            #pragma unroll
            for (int f = 0; f < 4; ++f) {
                short8 bk_ = *(const short8*)((char*)smem + d * 8192 + swzb(f * 16 + m16, jj * 4 + g));
                s[f] = MFMA16(aqj, bk_, s[f], 0, 0, 0);
            }
        }

        // online softmax (base-2 domain; log2e folded into Q scale)
        float tmax[4], scal[4], tsum[4];
        #pragma unroll
        for (int i = 0; i < 4; ++i)
            tmax[i] = fmaxf(fmaxf(s[0][i], s[1][i]), fmaxf(s[2][i], s[3][i]));
        #pragma unroll
        for (int xm = 1; xm < 16; xm <<= 1)
            #pragma unroll
            for (int i = 0; i < 4; ++i)
                tmax[i] = fmaxf(tmax[i], __shfl_xor(tmax[i], xm, 64));
        #pragma unroll
        for (int i = 0; i < 4; ++i) {
            float mnew = fmaxf(mrun[i], tmax[i]);
            scal[i] = exp2f(mrun[i] - mnew);
            mrun[i] = mnew;
        }
        #pragma unroll
        for (int f = 0; f < 4; ++f)
            #pragma unroll
            for (int i = 0; i < 4; ++i)
                s[f][i] = exp2f(s[f][i] - mrun[i]);
        #pragma unroll
        for (int i = 0; i < 4; ++i)
            tsum[i] = s[0][i] + s[1][i] + s[2][i] + s[3][i];
        #pragma unroll
        for (int xm = 1; xm < 16; xm <<= 1)
            #pragma unroll
            for (int i = 0; i < 4; ++i)
                tsum[i] += __shfl_xor(tsum[i], xm, 64);
        #pragma unroll
        for (int i = 0; i < 4; ++i)
            lrun[i] = lrun[i] * scal[i] + tsum[i];
        #pragma unroll
        for (int f = 0; f < 4; ++f)
            #pragma unroll
            for (int i = 0; i < 4; ++i)
                accO[f][i] *= scal[i];

        // P -> wave-private sP (swizzled), re-read as A fragments (no barrier)
        #pragma unroll
        for (int f = 0; f < 4; ++f)
            #pragma unroll
            for (int i = 0; i < 4; ++i) {
                int r = g * 4 + i, c = f * 16 + m16;
                *(ushort_t*)((char*)smem + spbase + r * 128
                    + (((((c >> 3) ^ (r & 7)) & 7) << 4) | ((c & 7) << 1))) = f2bf(s[f][i]);
            }
        short8 pa0 = *(const short8*)((char*)smem + spbase + m16 * 128 + (((g ^ (m16 & 7)) & 7) << 4));
        short8 pa1 = *(const short8*)((char*)smem + spbase + m16 * 128 + ((((4 + g) ^ (m16 & 7)) & 7) << 4));

        // O += P V
        #pragma unroll
        for (int jj = 0; jj < 2; ++jj) {
            short8 paj = jj ? pa1 : pa0;
            #pragma unroll
            for (int f = 0; f < 4; ++f) {
                short8 bv_ = *(const short8*)((char*)smem + 16384 + d * 8192 + swzb(f * 16 + m16, jj * 4 + g));
                accO[f] = MFMA16(paj, bv_, accO[f], 0, 0, 0);
            }
        }
        __syncthreads();
    }

    float inv[4];
    #pragma unroll
    for (int i = 0; i < 4; ++i) inv[i] = 1.0f / lrun[i];
    float* orow = out + ((size_t)b * 576 + p0 + w * 16) * 768 + h * 64;
    #pragma unroll
    for (int f = 0; f < 4; ++f)
        #pragma unroll
        for (int i = 0; i < 4; ++i)
            orow[(size_t)(g * 4 + i) * 768 + f * 16 + m16] = accO[f][i] * inv[i];
}

extern "C" void kernel_launch(void* const* d_in, const int* in_sizes, int n_in,
                              void* d_out, int out_size, void* d_ws, size_t ws_size,
                              hipStream_t stream) {
    const float* x  = (const float*)d_in[0];
    const float* Wq = (const float*)d_in[1];
    const float* bq = (const float*)d_in[2];
    const float* Wk = (const float*)d_in[3];
    const float* bk = (const float*)d_in[4];
    const float* Wv = (const float*)d_in[5];
    const float* bv = (const float*)d_in[6];
    float* out = (float*)d_out;

    ushort_t* Wt  = (ushort_t*)d_ws;
    ushort_t* Kb  = (ushort_t*)((char*)d_ws + WT_BYTES);
    ushort_t* Vtb = (ushort_t*)((char*)d_ws + WT_BYTES + KV_BYTES);
    ushort_t* Qb  = (ushort_t*)((char*)d_ws + WT_BYTES + 2 * (size_t)KV_BYTES);

    const bool bigws = ws_size >= (size_t)WT_BYTES + 3 * (size_t)KV_BYTES;  // 88,473,600

    hipLaunchKernelGGL(prep_w, dim3(864), dim3(256), 0, stream, Wq, Wk, Wv, Wt);
    if (bigws) {
        hipLaunchKernelGGL(proj_qkv, dim3(18, 192), dim3(256), 0, stream,
                           x, Wt, bq, bk, bv, Qb, Kb, Vtb, 18, 0);
        hipLaunchKernelGGL((attn_k<0>), dim3(9, 384), dim3(256), 0, stream,
                           x, Wt, bq, Qb, Kb, Vtb, out);
    } else {
        hipLaunchKernelGGL(proj_qkv, dim3(12, 192), dim3(256), 0, stream,
                           x, Wt, bq, bk, bv, Qb, Kb, Vtb, 12, 12);
        hipLaunchKernelGGL((attn_k<1>), dim3(9, 384), dim3(256), 0, stream,
                           x, Wt, bq, Qb, Kb, Vtb, out);
    }
}